// Round 1
// baseline (234.838 us; speedup 1.0000x reference)
//
#include <hip/hip_runtime.h>

// Problem: B=8192, L=512, P=64, S=32, O=200
// Outputs (flat): [min1, min2, sub_min1, sub_min2, out(8192x200)]
//
// Insight: d_all[B,P,S] is only ever consumed at p == idx[b] (member mask /
// take_along_axis), so we never materialize it. Per sample: 64 proto dots,
// 32 sub-proto dots (selected group only), 200-wide expert GEMV.

#define NL 512
#define NP 64
#define NS 32
#define NO 200
#define NB 8192

// ws layout (4-byte units):
// [0]          sum_dmin (float, atomicAdd)
// [1..64]      colmin   (uint, monotone-encoded float, atomicMin)  -> min2
// [65..2112]   submin   (uint encoded, P*S)                        -> sub_min1
// [2113..2176] grp_sum  (float, atomicAdd)                         -> sub_min2
// [2177..2240] counts   (uint, atomicAdd)
// [2241..2304] pp   = ||proto_p||^2
// [2305..4352] sp2  = ||sub_proto_{p,s}||^2

__device__ __forceinline__ unsigned encf(float f) {
  unsigned u = __float_as_uint(f);
  return (u & 0x80000000u) ? ~u : (u | 0x80000000u);
}
__device__ __forceinline__ float decf(unsigned m) {
  return __uint_as_float((m & 0x80000000u) ? (m ^ 0x80000000u) : ~m);
}
__device__ __forceinline__ float wred(float v) {
#pragma unroll
  for (int m = 32; m >= 1; m >>= 1) v += __shfl_xor(v, m, 64);
  return v;
}
__device__ __forceinline__ float dot8(const float4& a0, const float4& a1,
                                      const float4& b0, const float4& b1) {
  return a0.x * b0.x + a0.y * b0.y + a0.z * b0.z + a0.w * b0.w +
         a1.x * b1.x + a1.y * b1.y + a1.z * b1.z + a1.w * b1.w;
}

__global__ void hier_init(float* __restrict__ ws) {
  int t = blockIdx.x * 256 + threadIdx.x;  // grid 9 blocks -> 2304 threads
  unsigned* wsu = (unsigned*)ws;
  if (t == 0) ws[0] = 0.f;
  if (t < 64) {
    ws[2113 + t] = 0.f;          // grp_sum
    wsu[2177 + t] = 0u;          // counts
    wsu[1 + t] = 0xFFFFFFFFu;    // colmin
  }
  if (t < 2048) wsu[65 + t] = 0xFFFFFFFFu;  // submin
}

// one wave per row; rows 0..63 = prototypes, 64..2111 = sub-prototypes
__global__ __launch_bounds__(256) void hier_norms(const float* __restrict__ proto,
                                                  const float* __restrict__ subp,
                                                  float* __restrict__ ws) {
  const int lane = threadIdx.x & 63;
  const int wid = (blockIdx.x << 2) + (threadIdx.x >> 6);
  if (wid >= NP + NP * NS) return;
  const float* row = (wid < NP) ? (proto + (size_t)wid * NL)
                                : (subp + (size_t)(wid - NP) * NL);
  const float4* rv = (const float4*)row;
  float4 a = rv[2 * lane], b = rv[2 * lane + 1];
  float s = wred(dot8(a, b, a, b));
  if (lane == 0) {
    if (wid < NP) ws[2241 + wid] = s;
    else          ws[2305 + (wid - NP)] = s;
  }
}

// one wave per 4 samples
__global__ __launch_bounds__(256) void hier_main(
    const float* __restrict__ x, const float* __restrict__ proto,
    const float* __restrict__ subp, const float* __restrict__ Wm,
    const float* __restrict__ bias, float* __restrict__ out,
    float* __restrict__ ws) {
  const int lane = threadIdx.x & 63;
  const int wid = (blockIdx.x << 2) + (threadIdx.x >> 6);  // 0..2047
  const int b0 = wid << 2;

  float* sum_dmin = ws;
  unsigned* colmin = (unsigned*)ws + 1;
  unsigned* submin = (unsigned*)ws + 65;
  float* grp_sum = ws + 2113;
  unsigned* counts = (unsigned*)ws + 2177;
  const float* pp = ws + 2241;
  const float* sp2 = ws + 2305;

  // x rows in registers: lane holds elements [8*lane .. 8*lane+7]
  float4 xa[4][2];
  float ss[4];
#pragma unroll
  for (int t = 0; t < 4; t++) {
    const float4* xv = (const float4*)(x + (size_t)(b0 + t) * NL);
    xa[t][0] = xv[2 * lane];
    xa[t][1] = xv[2 * lane + 1];
    ss[t] = wred(dot8(xa[t][0], xa[t][1], xa[t][0], xa[t][1]));
  }

  // ---- phase 1: d_top over 64 prototypes ----
  float dmin[4] = {1e30f, 1e30f, 1e30f, 1e30f};
  int gi[4] = {0, 0, 0, 0};
  float colml = 1e30f;  // lane p tracks running min of column p
  const float4* pv = (const float4*)proto;
  for (int p = 0; p < NP; p++) {
    float4 pr0 = pv[p * (NL / 4) + 2 * lane];
    float4 pr1 = pv[p * (NL / 4) + 2 * lane + 1];
    float ppv = pp[p];
    float m4 = 1e30f;
#pragma unroll
    for (int t = 0; t < 4; t++) {
      float d = wred(dot8(xa[t][0], xa[t][1], pr0, pr1));
      float dt = ss[t] + ppv - 2.0f * d;
      if (dt < dmin[t]) { dmin[t] = dt; gi[t] = p; }  // strict <: first-min, matches argmin
      m4 = fminf(m4, dt);
    }
    if (lane == p) colml = fminf(colml, m4);
  }
  atomicMin(&colmin[lane], encf(colml));
  if (lane == 0) atomicAdd(sum_dmin, dmin[0] + dmin[1] + dmin[2] + dmin[3]);

  // ---- phase 2: selected-group sub-distances + expert GEMV ----
#pragma unroll
  for (int t = 0; t < 4; t++) {
    const int g = gi[t];
    const float4* sv = (const float4*)(subp + (size_t)g * NS * NL);
    const float* s2 = sp2 + g * NS;
    float dsel[NS];  // uniform across lanes (post-reduction)
    float msel = 1e30f, myds = 0.f;
#pragma unroll
    for (int s = 0; s < NS; s++) {
      float4 a0 = sv[s * (NL / 4) + 2 * lane];
      float4 a1 = sv[s * (NL / 4) + 2 * lane + 1];
      float d = wred(dot8(xa[t][0], xa[t][1], a0, a1));
      float dv = ss[t] + s2[s] - 2.0f * d;
      dsel[s] = dv;
      msel = fminf(msel, dv);
      if (lane == s) myds = dv;  // lane s keeps d_sel[s] for the scatter-min
    }
    if (lane == 0) {
      atomicAdd(&grp_sum[g], msel);
      atomicAdd(&counts[g], 1u);
    }
    if (lane < NS) atomicMin(&submin[g * NS + lane], encf(myds));

    const float4* wv = (const float4*)(Wm + (size_t)g * NO * NS);
    const float* bv = bias + g * NO;
#pragma unroll
    for (int og = 0; og < 4; og++) {
      int o = (og << 6) + lane;
      if (o < NO) {
        float acc = bv[o];
#pragma unroll
        for (int k = 0; k < 8; k++) {
          float4 w4 = wv[o * 8 + k];
          acc += dsel[4 * k + 0] * w4.x + dsel[4 * k + 1] * w4.y +
                 dsel[4 * k + 2] * w4.z + dsel[4 * k + 3] * w4.w;
        }
        out[(size_t)(b0 + t) * NO + o] = acc;
      }
    }
  }
}

__global__ void hier_final(const float* __restrict__ ws, float* __restrict__ out4) {
  const int lane = threadIdx.x;  // 64 threads, 1 wave
  const unsigned* colmin = (const unsigned*)ws + 1;
  const unsigned* submin = (const unsigned*)ws + 65;
  const float* grp_sum = ws + 2113;
  const unsigned* counts = (const unsigned*)ws + 2177;

  float min2 = wred(decf(colmin[lane])) * (1.0f / NP);

  unsigned c = counts[lane];
  float s32 = 0.f;
#pragma unroll
  for (int s = 0; s < NS; s++) s32 += decf(submin[lane * NS + s]);
  float sub1 = wred((c > 0u) ? s32 * (1.0f / NS) : 0.f) * (1.0f / NP);
  float sub2 = wred((c > 0u) ? grp_sum[lane] / (float)c : 0.f) * (1.0f / NP);

  if (lane == 0) {
    out4[0] = ws[0] * (1.0f / NB);
    out4[1] = min2;
    out4[2] = sub1;
    out4[3] = sub2;
  }
}

extern "C" void kernel_launch(void* const* d_in, const int* in_sizes, int n_in,
                              void* d_out, int out_size, void* d_ws, size_t ws_size,
                              hipStream_t stream) {
  const float* x = (const float*)d_in[0];
  const float* proto = (const float*)d_in[1];
  const float* subp = (const float*)d_in[2];
  const float* Wm = (const float*)d_in[3];
  const float* bias = (const float*)d_in[4];
  float* outf = (float*)d_out;
  float* ws = (float*)d_ws;

  hipLaunchKernelGGL(hier_init, dim3(9), dim3(256), 0, stream, ws);
  hipLaunchKernelGGL(hier_norms, dim3(528), dim3(256), 0, stream, proto, subp, ws);
  hipLaunchKernelGGL(hier_main, dim3(512), dim3(256), 0, stream,
                     x, proto, subp, Wm, bias, outf + 4, ws);
  hipLaunchKernelGGL(hier_final, dim3(1), dim3(64), 0, stream, ws, outf);
}